// Round 1
// 538.512 us; speedup vs baseline: 1.0045x; 1.0045x over previous
//
#include <hip/hip_runtime.h>
#include <hip/hip_bf16.h>

// ScaledDotProductAttention: B=64, Lq=Lk=1024, D=64, temperature=8
// out = [output (64*1024*64 fp32) | attn (64*1024*1024 fp32)]

typedef __attribute__((ext_vector_type(8))) short bf16x8;
typedef __attribute__((ext_vector_type(4))) short bf16x4;
typedef __attribute__((ext_vector_type(4))) float f32x4;
typedef __attribute__((ext_vector_type(4))) int   i32x4;

#define GLOBAL_AS __attribute__((address_space(1)))
#define LDS_AS    __attribute__((address_space(3)))

static __device__ __forceinline__ short f2bf(float f) {
    return (short)__builtin_bit_cast(unsigned short, __float2bfloat16(f));
}
static __device__ __forceinline__ bf16x8 pack8(float4 a, float4 b) {
    union { bf16x8 v; __hip_bfloat162 h[4]; } u;
    u.h[0] = __float22bfloat162_rn(make_float2(a.x, a.y));
    u.h[1] = __float22bfloat162_rn(make_float2(a.z, a.w));
    u.h[2] = __float22bfloat162_rn(make_float2(b.x, b.y));
    u.h[3] = __float22bfloat162_rn(make_float2(b.z, b.w));
    return u.v;
}
static __device__ __forceinline__ bf16x8 pack8v(f32x4 a, f32x4 b) {
    union { bf16x8 v; __hip_bfloat162 h[4]; } u;
    u.h[0] = __float22bfloat162_rn(make_float2(a[0], a[1]));
    u.h[1] = __float22bfloat162_rn(make_float2(a[2], a[3]));
    u.h[2] = __float22bfloat162_rn(make_float2(b[0], b[1]));
    u.h[3] = __float22bfloat162_rn(make_float2(b[2], b[3]));
    return u.v;
}
static __device__ __forceinline__ bf16x4 pack4(float a, float b, float c, float d) {
    union { bf16x4 v; __hip_bfloat162 h[2]; } u;
    u.h[0] = __float22bfloat162_rn(make_float2(a, b));
    u.h[1] = __float22bfloat162_rn(make_float2(c, d));
    return u.v;
}
static __device__ __forceinline__ f32x4 vscale(f32x4 a, float s) {
    a[0] *= s; a[1] *= s; a[2] *= s; a[3] *= s; return a;
}

// wave-wide 1KB async global->LDS copy: lds dest = uniform base + lane*16
static __device__ __forceinline__ void dma16(void* lds, const void* g) {
    __builtin_amdgcn_global_load_lds((const GLOBAL_AS unsigned*)g,
                                     (LDS_AS unsigned*)lds, 16, 0, 0);
}
// stage an 8KB tile (64 rows x 128B): 2 insts per wave
static __device__ __forceinline__ void stage8k(short* lds, const short* g, int w, int L) {
    dma16((void*)(lds + (w * 2 + 0) * 512), (const void*)(g + (w * 2 + 0) * 512 + L * 8));
    dma16((void*)(lds + (w * 2 + 1) * 512), (const void*)(g + (w * 2 + 1) * 512 + L * 8));
}

// ---------------------------------------------------------------------------
// pre-pass (fused): K fp32 -> bf16 swizzled tiles  |  V fp32 -> bf16 V^T swizzled tiles
// tile layout: [b*16+kt][row(64)][8 chunks of 8 shorts, chunk c stored at c^(row&7)]
__global__ __launch_bounds__(256) void pre_kv(const float* __restrict__ k,
                                              const float* __restrict__ v,
                                              short* __restrict__ kb,
                                              short* __restrict__ vt) {
    __shared__ short t[64][72];
    const int tid = threadIdx.x;
    if (blockIdx.x < 2048) {
        long ci = (long)blockIdx.x * 256 + tid;   // 524288 chunks of 8 floats
        long row = ci >> 3;                       // b*1024 + kpos
        int  c   = (int)(ci & 7);
        const f32x4* s = (const f32x4*)(k + row * 64 + c * 8);
        f32x4 a  = __builtin_nontemporal_load(s);
        f32x4 b2 = __builtin_nontemporal_load(s + 1);
        int r = (int)(row & 63);
        short* dst = kb + (row >> 6) * 4096 + (long)r * 64 + ((c ^ (r & 7)) << 3);
        *(bf16x8*)dst = pack8v(a, b2);
    } else {
        const int bkt = blockIdx.x - 2048;        // b*16 + kt
        const int row = tid >> 2;                 // kpos within tile
        const int cg  = (tid & 3) * 16;           // d start
        const float* src = v + ((long)bkt * 64 + row) * 64 + cg;
        f32x4 f0 = __builtin_nontemporal_load((const f32x4*)src);
        f32x4 f1 = __builtin_nontemporal_load((const f32x4*)src + 1);
        f32x4 f2 = __builtin_nontemporal_load((const f32x4*)src + 2);
        f32x4 f3 = __builtin_nontemporal_load((const f32x4*)src + 3);
        float vv[16] = {f0[0], f0[1], f0[2], f0[3], f1[0], f1[1], f1[2], f1[3],
                        f2[0], f2[1], f2[2], f2[3], f3[0], f3[1], f3[2], f3[3]};
        #pragma unroll
        for (int dd = 0; dd < 16; ++dd) t[cg + dd][row] = f2bf(vv[dd]);
        __syncthreads();
        const int d = tid >> 2, c0 = (tid & 3) * 2;
        short* dstrow = vt + (long)bkt * 4096 + d * 64;
        *(int4*)&dstrow[((c0 ^ (d & 7)) << 3)]       = *(int4*)&t[d][c0 * 8];
        *(int4*)&dstrow[(((c0 + 1) ^ (d & 7)) << 3)] = *(int4*)&t[d][c0 * 8 + 8];
    }
}

// ---------------------------------------------------------------------------
// main: S^T scheme. QK^T computed transposed (swap MFMA operands) so qrow = lane&15
// for every register. Sweep 1 now also streams the raw int32 mask (nontemporal,
// overlapping the K-DMA latency phase) and writes the packed 64-bit mask words to
// the workspace itself; sweep 2 consumes them exactly as before.
// XCD-aware block remap: 1024 linear blocks, lin&7 = XCD, each XCD owns 8 whole
// batches so K/V bf16 tiles stay L2-resident (2 MB working set / 4 MB L2).
__global__ __launch_bounds__(256, 4) void attn_main(
    const float* __restrict__ q, const int* __restrict__ mask,
    unsigned long long* __restrict__ bits,
    const short* __restrict__ kb, const short* __restrict__ vt,
    float* __restrict__ out, float* __restrict__ attn)
{
    __shared__ short kbuf[2][4096];     // 16 KB
    __shared__ short vbuf[2][4096];     // 16 KB
    __shared__ short ptile[4][1024];    // 8 KB (per-wave P round-trip, swizzled)

    const int tid  = threadIdx.x;
    const int w    = tid >> 6;
    const int L    = tid & 63;
    const int n    = L & 15;    // qrow within wave-tile (for ALL regs)
    const int g    = L >> 4;
    // XCD remap: round-robin dispatch => lin&7 = XCD; batches [xcd*8, xcd*8+8)
    const int lin  = blockIdx.x;                 // 0..1023
    const int b    = (lin & 7) * 8 + ((lin >> 3) >> 4);
    const int qt   = (lin >> 3) & 15;
    const long bq  = (long)b * 1024 + qt * 64;

    const short* ktg = kb + (long)b * 65536;
    const short* vtg = vt + (long)b * 65536;

    const long grow = bq + 16 * w + n;           // global q-row for this lane

    // Q fragments, scale = 1/8 * log2(e)  (exp(s) == exp2(s*log2e), exact identity)
    const float* qrow = q + grow * 64 + g * 8;
    f32x4 qa0 = ((const f32x4*)qrow)[0];
    f32x4 qa1 = ((const f32x4*)qrow)[1];
    f32x4 qb0 = ((const f32x4*)(qrow + 32))[0];
    f32x4 qb1 = ((const f32x4*)(qrow + 32))[1];
    const float sc = 0.125f * 1.4426950408889634f;
    qa0 = vscale(qa0, sc); qa1 = vscale(qa1, sc);
    qb0 = vscale(qb0, sc); qb1 = vscale(qb1, sc);
    bf16x8 qf0 = pack8v(qa0, qa1);
    bf16x8 qf1 = pack8v(qb0, qb1);

    const int* mbase = mask + grow * 1024 + g * 4;   // + kt*64 + t*16
    const int sw = (n & 7);  // row swizzle key for all 64-short LDS rows

    // ---------------- sweep 1: l per q-row + mask pack ----------------------
    float lp = 0.f;
    stage8k(kbuf[0], ktg, w, L);
    __syncthreads();

    for (int kt = 0; kt < 16; ++kt) {
        if (kt < 15) {
            stage8k(kbuf[(kt + 1) & 1], ktg + (kt + 1) * 4096, w, L);
        } else {  // prefetch sweep-2 tile 0
            stage8k(kbuf[0], ktg, w, L);
            stage8k(vbuf[0], vtg, w, L);
        }
        // stream this lane's 16 mask ints (cols kt*64 + t*16 + g*4 ..+3), read-once
        const int* mp = mbase + kt * 64;
        i32x4 mm0 = __builtin_nontemporal_load((const i32x4*)(mp));
        i32x4 mm1 = __builtin_nontemporal_load((const i32x4*)(mp + 16));
        i32x4 mm2 = __builtin_nontemporal_load((const i32x4*)(mp + 32));
        i32x4 mm3 = __builtin_nontemporal_load((const i32x4*)(mp + 48));

        const short* kl = kbuf[kt & 1];
        f32x4 acc[4];
        #pragma unroll
        for (int t = 0; t < 4; ++t) { acc[t][0]=0.f; acc[t][1]=0.f; acc[t][2]=0.f; acc[t][3]=0.f; }
        #pragma unroll
        for (int t = 0; t < 4; ++t) {
            // S^T tile: A = K rows (lane&15 = kpos), B = Q^T (lane&15 = qrow)
            bf16x8 kf0 = *(const bf16x8*)&kl[(t * 16 + n) * 64 + ((g ^ sw) << 3)];
            bf16x8 kf1 = *(const bf16x8*)&kl[(t * 16 + n) * 64 + (((4 + g) ^ sw) << 3)];
            acc[t] = __builtin_amdgcn_mfma_f32_16x16x32_bf16(kf0, qf0, acc[t], 0, 0, 0);
            acc[t] = __builtin_amdgcn_mfma_f32_16x16x32_bf16(kf1, qf1, acc[t], 0, 0, 0);
        }
        // nibbles: bit i = mask[row][kt*64 + t*16 + g*4 + i]
        unsigned nb[4];
        nb[0] = (mm0[0]!=0?1u:0u)|(mm0[1]!=0?2u:0u)|(mm0[2]!=0?4u:0u)|(mm0[3]!=0?8u:0u);
        nb[1] = (mm1[0]!=0?1u:0u)|(mm1[1]!=0?2u:0u)|(mm1[2]!=0?4u:0u)|(mm1[3]!=0?8u:0u);
        nb[2] = (mm2[0]!=0?1u:0u)|(mm2[1]!=0?2u:0u)|(mm2[2]!=0?4u:0u)|(mm2[3]!=0?8u:0u);
        nb[3] = (mm3[0]!=0?1u:0u)|(mm3[1]!=0?2u:0u)|(mm3[2]!=0?4u:0u)|(mm3[3]!=0?8u:0u);
        #pragma unroll
        for (int t = 0; t < 4; ++t)
            #pragma unroll
            for (int i = 0; i < 4; ++i)
                lp += ((nb[t] >> i) & 1u) ? 0.f : __builtin_exp2f(acc[t][i]);
        // assemble the per-(row,kt) 64-bit word (bit j = col kt*64+j) and store
        unsigned long long wword =
              ((unsigned long long)nb[0] << (g * 4))
            | ((unsigned long long)nb[1] << (16 + g * 4))
            | ((unsigned long long)nb[2] << (32 + g * 4))
            | ((unsigned long long)nb[3] << (48 + g * 4));
        wword |= __shfl_xor(wword, 16);
        wword |= __shfl_xor(wword, 32);
        if (g == 0) bits[grow * 16 + kt] = wword;
        __syncthreads();
    }
    float l = lp + __shfl_xor(lp, 16);
    l += __shfl_xor(l, 32);
    const float linv = 1.0f / l;

    // ---------------- sweep 2: P^T, attn stores, P@V ------------------------
    f32x4 oacc[4];
    #pragma unroll
    for (int u = 0; u < 4; ++u) { oacc[u][0]=0.f; oacc[u][1]=0.f; oacc[u][2]=0.f; oacc[u][3]=0.f; }

    const unsigned long long* mrow_ptr = bits + grow * 16;
    float* attn_row = attn + grow * 1024;
    short* pw = ptile[w];

    for (int kt = 0; kt < 16; ++kt) {
        if (kt < 15) {
            stage8k(kbuf[(kt + 1) & 1], ktg + (kt + 1) * 4096, w, L);
            stage8k(vbuf[(kt + 1) & 1], vtg + (kt + 1) * 4096, w, L);
        }
        unsigned long long mrow = mrow_ptr[kt];
        const short* kl = kbuf[kt & 1];
        const short* vl = vbuf[kt & 1];
        f32x4 acc[4];
        #pragma unroll
        for (int t = 0; t < 4; ++t) { acc[t][0]=0.f; acc[t][1]=0.f; acc[t][2]=0.f; acc[t][3]=0.f; }
        #pragma unroll
        for (int t = 0; t < 4; ++t) {
            bf16x8 kf0 = *(const bf16x8*)&kl[(t * 16 + n) * 64 + ((g ^ sw) << 3)];
            bf16x8 kf1 = *(const bf16x8*)&kl[(t * 16 + n) * 64 + (((4 + g) ^ sw) << 3)];
            acc[t] = __builtin_amdgcn_mfma_f32_16x16x32_bf16(kf0, qf0, acc[t], 0, 0, 0);
            acc[t] = __builtin_amdgcn_mfma_f32_16x16x32_bf16(kf1, qf1, acc[t], 0, 0, 0);
        }
        unsigned long long ms = mrow >> (g * 4);
        #pragma unroll
        for (int t = 0; t < 4; ++t) {
            unsigned b0 = (unsigned)(ms >> (t * 16 + 0)) & 1u;
            unsigned b1 = (unsigned)(ms >> (t * 16 + 1)) & 1u;
            unsigned b2 = (unsigned)(ms >> (t * 16 + 2)) & 1u;
            unsigned b3 = (unsigned)(ms >> (t * 16 + 3)) & 1u;
            float p0 = b0 ? 0.f : __builtin_exp2f(acc[t][0]) * linv;
            float p1 = b1 ? 0.f : __builtin_exp2f(acc[t][1]) * linv;
            float p2 = b2 ? 0.f : __builtin_exp2f(acc[t][2]) * linv;
            float p3 = b3 ? 0.f : __builtin_exp2f(acc[t][3]) * linv;
            // attn store: row = qrow(n), cols kt*64 + t*16 + g*4 .. +3 (fp32, 16B, nt)
            f32x4 pv; pv[0] = p0; pv[1] = p1; pv[2] = p2; pv[3] = p3;
            __builtin_nontemporal_store(pv, (f32x4*)(attn_row + kt * 64 + t * 16 + g * 4));
            // P^T -> LDS (A-layout source): row n, kpos t*16+g*4.. (b64, swizzled)
            *(bf16x4*)&pw[n * 64 + ((((t * 2) + (g >> 1)) ^ sw) << 3) + (g & 1) * 4] =
                pack4(p0, p1, p2, p3);
        }
        // read P as A-operand: lane holds P[qrow=n][kpos = g*8+j (+32)]
        bf16x8 pf0 = *(const bf16x8*)&pw[n * 64 + ((g ^ sw) << 3)];
        bf16x8 pf1 = *(const bf16x8*)&pw[n * 64 + (((4 + g) ^ sw) << 3)];
        // O = P @ V : B-frag = V^T rows (d = u*16+n), kpos chunks g / 4+g
        #pragma unroll
        for (int u = 0; u < 4; ++u) {
            bf16x8 vf0 = *(const bf16x8*)&vl[(u * 16 + n) * 64 + ((g ^ sw) << 3)];
            bf16x8 vf1 = *(const bf16x8*)&vl[(u * 16 + n) * 64 + (((4 + g) ^ sw) << 3)];
            oacc[u] = __builtin_amdgcn_mfma_f32_16x16x32_bf16(pf0, vf0, oacc[u], 0, 0, 0);
            oacc[u] = __builtin_amdgcn_mfma_f32_16x16x32_bf16(pf1, vf1, oacc[u], 0, 0, 0);
        }
        __syncthreads();
    }

    // O in C-layout: row g*4+i = qrow_local, col n = d within u-subtile
    #pragma unroll
    for (int u = 0; u < 4; ++u)
        #pragma unroll
        for (int i = 0; i < 4; ++i)
            __builtin_nontemporal_store(oacc[u][i],
                &out[(bq + 16 * w + g * 4 + i) * 64 + u * 16 + n]);
}

// ---------------------------------------------------------------------------
// fallback for small ws (round-1 kernel, known correct)
#define KSTRIDE 72
#define PSTRIDE 68
__global__ __launch_bounds__(256) void attn_fallback(
    const float* __restrict__ q, const float* __restrict__ k,
    const float* __restrict__ v, const int* __restrict__ mask,
    float* __restrict__ out, float* __restrict__ attn)
{
    __shared__ unsigned maskbits[64][32];
    __shared__ short kbuf[64 * KSTRIDE];
    __shared__ short vtbuf[64 * KSTRIDE];
    __shared__ float ptilef[4 * 16 * PSTRIDE];

    const int tid  = threadIdx.x;
    const int w    = tid >> 6;
    const int L    = tid & 63;
    const int n    = L & 15;
    const int quad = L >> 4;
    const int b    = blockIdx.y;
    const long bq  = (long)b * 1024 + blockIdx.x * 64;

    const float* qrow = q + (bq + 16 * w + n) * 64 + quad * 8;
    float4 qa0 = ((const float4*)qrow)[0];
    float4 qa1 = ((const float4*)(qrow + 4))[0];
    float4 qb0 = ((const float4*)(qrow + 32))[0];
    float4 qb1 = ((const float4*)(qrow + 36))[0];
    const float sc = 0.125f;
    qa0.x *= sc; qa0.y *= sc; qa0.z *= sc; qa0.w *= sc;
    qa1.x *= sc; qa1.y *= sc; qa1.z *= sc; qa1.w *= sc;
    qb0.x *= sc; qb0.y *= sc; qb0.z *= sc; qb0.w *= sc;
    qb1.x *= sc; qb1.y *= sc; qb1.z *= sc; qb1.w *= sc;
    bf16x8 qf0 = pack8(qa0, qa1);
    bf16x8 qf1 = pack8(qb0, qb1);

    #pragma unroll
    for (int ii = 0; ii < 8; ++ii) {
        int wi  = ii * 256 + tid;
        int row = wi >> 5;
        int wc  = wi & 31;
        const int4* mp = (const int4*)(mask + (bq + row) * 1024 + wc * 32);
        unsigned word = 0;
        #pragma unroll
        for (int j = 0; j < 8; ++j) {
            int4 m4 = mp[j];
            word |= (m4.x != 0 ? 1u : 0u) << (4 * j + 0);
            word |= (m4.y != 0 ? 1u : 0u) << (4 * j + 1);
            word |= (m4.z != 0 ? 1u : 0u) << (4 * j + 2);
            word |= (m4.w != 0 ? 1u : 0u) << (4 * j + 3);
        }
        maskbits[row][wc] = word;
    }

    float m_i[4] = {-1e30f, -1e30f, -1e30f, -1e30f};
    float l_i[4] = {0.f, 0.f, 0.f, 0.f};

    for (int kt = 0; kt < 16; ++kt) {
        __syncthreads();
        {
            const float* kr = k + ((long)b * 1024 + kt * 64 + L) * 64 + w * 16;
            float4 k0 = ((const float4*)kr)[0];
            float4 k1 = ((const float4*)kr)[1];
            float4 k2 = ((const float4*)kr)[2];
            float4 k3 = ((const float4*)kr)[3];
            bf16x8* dst = (bf16x8*)&kbuf[L * KSTRIDE + w * 16];
            dst[0] = pack8(k0, k1);
            dst[1] = pack8(k2, k3);
        }
        __syncthreads();
        f32x4 acc[4];
        #pragma unroll
        for (int t = 0; t < 4; ++t) { acc[t][0]=0.f; acc[t][1]=0.f; acc[t][2]=0.f; acc[t][3]=0.f; }
        #pragma unroll
        for (int t = 0; t < 4; ++t) {
            bf16x8 b0 = *(const bf16x8*)&kbuf[(t * 16 + n) * KSTRIDE + quad * 8];
            bf16x8 b1 = *(const bf16x8*)&kbuf[(t * 16 + n) * KSTRIDE + 32 + quad * 8];
            acc[t] = __builtin_amdgcn_mfma_f32_16x16x32_bf16(qf0, b0, acc[t], 0, 0, 0);
            acc[t] = __builtin_amdgcn_mfma_f32_16x16x32_bf16(qf1, b1, acc[t], 0, 0, 0);
        }
        #pragma unroll
        for (int i = 0; i < 4; ++i) {
            int mrow = 16 * w + quad * 4 + i;
            unsigned w0 = maskbits[mrow][kt * 2];
            unsigned w1 = maskbits[mrow][kt * 2 + 1];
            float s0 = ((w0 >> n)        & 1u) ? -1e30f : acc[0][i];
            float s1 = ((w0 >> (16 + n)) & 1u) ? -1e30f : acc[1][i];
            float s2 = ((w1 >> n)        & 1u) ? -1e30f : acc[2][i];
            float s3 = ((w1 >> (16 + n)) & 1u) ? -1e30f : acc[3][i];
            float mt = fmaxf(fmaxf(s0, s1), fmaxf(s2, s3));
            mt = fmaxf(mt, __shfl_xor(mt, 1));
            mt = fmaxf(mt, __shfl_xor(mt, 2));
            mt = fmaxf(mt, __shfl_xor(mt, 4));
            mt = fmaxf(mt, __shfl_xor(mt, 8));
            float mnew = fmaxf(m_i[i], mt);
            float ps = __expf(s0 - mnew) + __expf(s1 - mnew)
                     + __expf(s2 - mnew) + __expf(s3 - mnew);
            ps += __shfl_xor(ps, 1);
            ps += __shfl_xor(ps, 2);
            ps += __shfl_xor(ps, 4);
            ps += __shfl_xor(ps, 8);
            l_i[i] = l_i[i] * __expf(m_i[i] - mnew) + ps;
            m_i[i] = mnew;
        }
    }
    float linv[4];
    #pragma unroll
    for (int i = 0; i < 4; ++i) linv[i] = 1.0f / l_i[i];

    f32x4 oacc[4];
    #pragma unroll
    for (int t = 0; t < 4; ++t) { oacc[t][0]=0.f; oacc[t][1]=0.f; oacc[t][2]=0.f; oacc[t][3]=0.f; }
    float* attn_row = attn + (bq + 16 * w + n) * 1024;

    for (int kt = 0; kt < 16; ++kt) {
        __syncthreads();
        {
            const float* kr = k + ((long)b * 1024 + kt * 64 + L) * 64 + w * 16;
            float4 k0 = ((const float4*)kr)[0];
            float4 k1 = ((const float4*)kr)[1];
            float4 k2 = ((const float4*)kr)[2];
            float4 k3 = ((const float4*)kr)[3];
            bf16x8* dst = (bf16x8*)&kbuf[L * KSTRIDE + w * 16];
            dst[0] = pack8(k0, k1);
            dst[1] = pack8(k2, k3);
            const float* vr = v + ((long)b * 1024 + kt * 64 + L) * 64 + w * 16;
            float4 v0 = ((const float4*)vr)[0];
            float4 v1 = ((const float4*)vr)[1];
            float4 v2 = ((const float4*)vr)[2];
            float4 v3 = ((const float4*)vr)[3];
            float vv[16] = {v0.x, v0.y, v0.z, v0.w, v1.x, v1.y, v1.z, v1.w,
                            v2.x, v2.y, v2.z, v2.w, v3.x, v3.y, v3.z, v3.w};
            #pragma unroll
            for (int dd = 0; dd < 16; ++dd)
                vtbuf[(w * 16 + dd) * KSTRIDE + L] = f2bf(vv[dd]);
        }
        __syncthreads();
        f32x4 acc[4];
        #pragma unroll
        for (int t = 0; t < 4; ++t) { acc[t][0]=0.f; acc[t][1]=0.f; acc[t][2]=0.f; acc[t][3]=0.f; }
        #pragma unroll
        for (int t = 0; t < 4; ++t) {
            bf16x8 b0 = *(const bf16x8*)&kbuf[(t * 16 + n) * KSTRIDE + quad * 8];
            bf16x8 b1 = *(const bf16x8*)&kbuf[(t * 16 + n) * KSTRIDE + 32 + quad * 8];
            acc[t] = __builtin_amdgcn_mfma_f32_16x16x32_bf16(qf0, b0, acc[t], 0, 0, 0);
            acc[t] = __builtin_amdgcn_mfma_f32_16x16x32_bf16(qf1, b1, acc[t], 0, 0, 0);
        }
        #pragma unroll
        for (int i = 0; i < 4; ++i) {
            int mrow = 16 * w + quad * 4 + i;
            unsigned w0 = maskbits[mrow][kt * 2];
            unsigned w1 = maskbits[mrow][kt * 2 + 1];
            float s0 = ((w0 >> n)        & 1u) ? -1e30f : acc[0][i];
            float s1 = ((w0 >> (16 + n)) & 1u) ? -1e30f : acc[1][i];
            float s2 = ((w1 >> n)        & 1u) ? -1e30f : acc[2][i];
            float s3 = ((w1 >> (16 + n)) & 1u) ? -1e30f : acc[3][i];
            float* pr = &ptilef[(w * 16 + quad * 4 + i) * PSTRIDE];
            pr[n]      = __expf(s0 - m_i[i]) * linv[i];
            pr[16 + n] = __expf(s1 - m_i[i]) * linv[i];
            pr[32 + n] = __expf(s2 - m_i[i]) * linv[i];
            pr[48 + n] = __expf(s3 - m_i[i]) * linv[i];
        }
        bf16x8 pf[2];
        #pragma unroll
        for (int c = 0; c < 2; ++c) {
            const float* pp = &ptilef[(w * 16 + n) * PSTRIDE + c * 32 + quad * 8];
            float4 p0 = ((const float4*)pp)[0];
            float4 p1 = ((const float4*)pp)[1];
            float* ap = attn_row + kt * 64 + c * 32 + quad * 8;
            ((float4*)ap)[0] = p0;
            ((float4*)ap)[1] = p1;
            pf[c] = pack8(p0, p1);
        }
        #pragma unroll
        for (int t = 0; t < 4; ++t) {
            bf16x8 vb0 = *(const bf16x8*)&vtbuf[(t * 16 + n) * KSTRIDE + quad * 8];
            bf16x8 vb1 = *(const bf16x8*)&vtbuf[(t * 16 + n) * KSTRIDE + 32 + quad * 8];
            oacc[t] = __builtin_amdgcn_mfma_f32_16x16x32_bf16(pf[0], vb0, oacc[t], 0, 0, 0);
            oacc[t] = __builtin_amdgcn_mfma_f32_16x16x32_bf16(pf[1], vb1, oacc[t], 0, 0, 0);
        }
    }
    #pragma unroll
    for (int t = 0; t < 4; ++t)
        #pragma unroll
        for (int i = 0; i < 4; ++i)
            out[(bq + 16 * w + quad * 4 + i) * 64 + t * 16 + n] = oacc[t][i];
}

extern "C" void kernel_launch(void* const* d_in, const int* in_sizes, int n_in,
                              void* d_out, int out_size, void* d_ws, size_t ws_size,
                              hipStream_t stream) {
    const float* q    = (const float*)d_in[0];
    const float* k    = (const float*)d_in[1];
    const float* v    = (const float*)d_in[2];
    const int*   mask = (const int*)d_in[3];
    float* out  = (float*)d_out;
    float* attn = out + (long)64 * 1024 * 64;

    const size_t need = (size_t)24 << 20;  // 8MB bits + 8MB K bf16 + 8MB V^T bf16
    if (ws_size >= need) {
        unsigned char* ws = (unsigned char*)d_ws;
        unsigned long long* bits = (unsigned long long*)ws;
        short* kbw = (short*)(ws + ((size_t)8 << 20));
        short* vtw = (short*)(ws + ((size_t)16 << 20));
        pre_kv<<<3072, 256, 0, stream>>>(k, v, kbw, vtw);
        attn_main<<<dim3(1024, 1, 1), dim3(256, 1, 1), 0, stream>>>(
            q, mask, bits, kbw, vtw, out, attn);
    } else {
        attn_fallback<<<dim3(16, 64, 1), dim3(256, 1, 1), 0, stream>>>(
            q, k, v, mask, out, attn);
    }
}